// Round 1
// baseline (942.207 us; speedup 1.0000x reference)
//
#include <hip/hip_runtime.h>
#include <hip/hip_bf16.h>
#include <math.h>

// ---------------------------------------------------------------------------
// VQ-VAE forward: encoder(3 convs+BN+ReLU) -> VQ -> decoder(3 convT+BN/sigmoid)
// B=64, CIN=3, H=W=256, K=512, D=4. All f32.
// Outputs concat: latents[262144] | quantized[262144] | decoded[12582912] | cb[1] | cm[1]
// ---------------------------------------------------------------------------

#define EPSV 1e-5f

// Block-wide sum (256 threads, wave64). Result valid on thread 0.
__device__ __forceinline__ float blockReduceSum(float v) {
    __shared__ float sbuf[8];
    #pragma unroll
    for (int o = 32; o > 0; o >>= 1) v += __shfl_down(v, o, 64);
    const int lane = threadIdx.x & 63, wid = threadIdx.x >> 6;
    if (lane == 0) sbuf[wid] = v;
    __syncthreads();
    float r = 0.f;
    if (threadIdx.x == 0) {
        const int nw = (blockDim.x + 63) >> 6;
        for (int i = 0; i < nw; ++i) r += sbuf[i];
    }
    __syncthreads();   // make helper safely re-callable
    return r;
}

// ---------------- direct conv (NCHW, OIHW), one thread per output pixel ------
template<int CIN, int COUT, int KH, int KW, int S, int P,
         int IH, int IW, int OH, int OW>
__global__ __launch_bounds__(256)
void conv_fwd(const float* __restrict__ in, const float* __restrict__ w,
              float* __restrict__ out) {
    __shared__ float wl[CIN * KH * KW];
    const int co = blockIdx.y;
    const int n  = blockIdx.z;
    for (int i = threadIdx.x; i < CIN * KH * KW; i += blockDim.x)
        wl[i] = w[co * CIN * KH * KW + i];
    __syncthreads();

    const int p = blockIdx.x * blockDim.x + threadIdx.x;
    if (p >= OH * OW) return;
    const int oy = p / OW, ox = p % OW;
    const int iy0 = oy * S - P, ix0 = ox * S - P;
    const float* inb = in + (size_t)n * CIN * IH * IW;

    float acc = 0.f;
    #pragma unroll
    for (int ci = 0; ci < CIN; ++ci) {
        #pragma unroll
        for (int kh = 0; kh < KH; ++kh) {
            const int iy = iy0 + kh;
            if (iy < 0 || iy >= IH) continue;
            #pragma unroll
            for (int kw = 0; kw < KW; ++kw) {
                const int ix = ix0 + kw;
                if (ix < 0 || ix >= IW) continue;
                acc += inb[(ci * IH + iy) * IW + ix] * wl[(ci * KH + kh) * KW + kw];
            }
        }
    }
    out[(((size_t)n * COUT + co) * OH + oy) * OW + ox] = acc;
}

// ---------------- transposed conv (weights: CIN,COUT,KH,KW) -----------------
template<int CIN, int COUT, int KH, int KW, int S, int P,
         int IH, int IW, int OH, int OW, bool SIGMOID>
__global__ __launch_bounds__(256)
void convT_fwd(const float* __restrict__ in, const float* __restrict__ w,
               const float* __restrict__ bias, float* __restrict__ out) {
    __shared__ float wl[CIN * KH * KW];   // gathered for this co
    const int co = blockIdx.y;
    const int n  = blockIdx.z;
    for (int i = threadIdx.x; i < CIN * KH * KW; i += blockDim.x) {
        const int ci = i / (KH * KW), r = i % (KH * KW);
        wl[i] = w[(ci * COUT + co) * KH * KW + r];
    }
    __syncthreads();

    const int p = blockIdx.x * blockDim.x + threadIdx.x;
    if (p >= OH * OW) return;
    const int oy = p / OW, ox = p % OW;
    const float* inb = in + (size_t)n * CIN * IH * IW;

    float acc = 0.f;
    #pragma unroll
    for (int kh = 0; kh < KH; ++kh) {
        const int t = oy + P - kh;
        if (t < 0 || (t & (S - 1)) || (t / S) >= IH) continue;
        const int iy = t / S;
        #pragma unroll
        for (int kw = 0; kw < KW; ++kw) {
            const int u = ox + P - kw;
            if (u < 0 || (u & (S - 1)) || (u / S) >= IW) continue;
            const int ix = u / S;
            #pragma unroll
            for (int ci = 0; ci < CIN; ++ci)
                acc += inb[(ci * IH + iy) * IW + ix] * wl[(ci * KH + kh) * KW + kw];
        }
    }
    if (SIGMOID) {
        acc += bias[co];
        acc = 1.f / (1.f + expf(-acc));
    }
    out[(((size_t)n * COUT + co) * OH + oy) * OW + ox] = acc;
}

// ---------------- per-channel batch-stat reduction (2 stages) ---------------
// Stage A: grid (C, N); each block reduces one (c,n) HW-slab.
template<int C, int HW>
__global__ __launch_bounds__(256)
void red_partial_k(const float* __restrict__ x, float* __restrict__ psum,
                   float* __restrict__ psq) {
    const int c = blockIdx.x, n = blockIdx.y;
    const float* base = x + ((size_t)n * C + c) * HW;
    float s = 0.f, q = 0.f;
    for (int i = threadIdx.x; i < HW; i += blockDim.x) {
        const float v = base[i];
        s += v; q += v * v;
    }
    s = blockReduceSum(s);
    q = blockReduceSum(q);
    if (threadIdx.x == 0) {
        psum[c * gridDim.y + n] = s;
        psq [c * gridDim.y + n] = q;
    }
}

// Stage B: grid C blocks of 64; emits per-channel scale/shift (BN folded).
template<int C>
__global__ __launch_bounds__(64)
void red_final_k(const float* __restrict__ psum, const float* __restrict__ psq,
                 const float* __restrict__ g, const float* __restrict__ b,
                 float* __restrict__ ss, float inv_count, int NB) {
    const int c = blockIdx.x;
    float s = 0.f, q = 0.f;
    for (int i = threadIdx.x; i < NB; i += 64) { s += psum[c * NB + i]; q += psq[c * NB + i]; }
    #pragma unroll
    for (int o = 32; o > 0; o >>= 1) {
        s += __shfl_down(s, o, 64);
        q += __shfl_down(q, o, 64);
    }
    if (threadIdx.x == 0) {
        const float mean = s * inv_count;
        const float var  = q * inv_count - mean * mean;
        const float rstd = 1.f / sqrtf(var + EPSV);
        const float sc   = g[c] * rstd;
        ss[2 * c]     = sc;
        ss[2 * c + 1] = b[c] - mean * sc;
    }
}

// ---------------- fused BN(scale/shift) + ReLU ------------------------------
template<int C, int HW>
__global__ __launch_bounds__(256)
void bnrelu_k(const float* __restrict__ in, float* __restrict__ out,
              const float* __restrict__ ss, int total) {
    const int i = blockIdx.x * blockDim.x + threadIdx.x;
    if (i >= total) return;
    const int c = (i / HW) % C;
    const float v = in[i] * ss[2 * c] + ss[2 * c + 1];
    out[i] = v > 0.f ? v : 0.f;
}

// ---------------- vector quantization ---------------------------------------
// latents NCHW [64,4,32,32] -> tokens [65536,4]; codebook [512,4] in LDS.
__global__ __launch_bounds__(256)
void vq_k(const float* __restrict__ latents, const float* __restrict__ emb,
          float* __restrict__ quantized, float* __restrict__ loss_partial) {
    __shared__ float e[512 * 4];
    __shared__ float ee[512];
    for (int i = threadIdx.x; i < 512 * 4; i += 256) e[i] = emb[i];
    __syncthreads();
    for (int k = threadIdx.x; k < 512; k += 256) {
        float s = 0.f;
        #pragma unroll
        for (int d = 0; d < 4; ++d) { const float v = e[k * 4 + d]; s += v * v; }
        ee[k] = s;
    }
    __syncthreads();

    const int t = blockIdx.x * 256 + threadIdx.x;     // token id, exactly 65536
    const int b = t >> 10, p = t & 1023;
    const float* lb = latents + ((size_t)b * 4) * 1024 + p;
    const float z0 = lb[0], z1 = lb[1024], z2 = lb[2048], z3 = lb[3072];
    const float zz = z0 * z0 + z1 * z1 + z2 * z2 + z3 * z3;

    int best = 0;
    float bd = INFINITY;
    #pragma unroll 8
    for (int k = 0; k < 512; ++k) {
        const float dot = z0 * e[k * 4] + z1 * e[k * 4 + 1] + z2 * e[k * 4 + 2] + z3 * e[k * 4 + 3];
        const float d = zz - 2.f * dot + ee[k];       // expanded form, as reference
        if (d < bd) { bd = d; best = k; }             // strict < == first-occurrence argmin
    }
    const float q0 = e[best * 4], q1 = e[best * 4 + 1], q2 = e[best * 4 + 2], q3 = e[best * 4 + 3];
    float* qb = quantized + ((size_t)b * 4) * 1024 + p;
    qb[0] = q0; qb[1024] = q1; qb[2048] = q2; qb[3072] = q3;

    const float ssd = (q0 - z0) * (q0 - z0) + (q1 - z1) * (q1 - z1)
                    + (q2 - z2) * (q2 - z2) + (q3 - z3) * (q3 - z3);
    const float bs = blockReduceSum(ssd);
    if (threadIdx.x == 0) loss_partial[blockIdx.x] = bs;
}

__global__ __launch_bounds__(256)
void loss_final_k(const float* __restrict__ partial, float* __restrict__ out_cb,
                  float* __restrict__ out_cm) {
    float s = partial[threadIdx.x];                    // exactly 256 partials
    s = blockReduceSum(s);
    if (threadIdx.x == 0) {
        const float L = s * (1.f / 262144.f);          // mean over N*D = 65536*4
        *out_cb = L;
        *out_cm = L;
    }
}

// ---------------------------------------------------------------------------
extern "C" void kernel_launch(void* const* d_in, const int* in_sizes, int n_in,
                              void* d_out, int out_size, void* d_ws, size_t ws_size,
                              hipStream_t stream) {
    const float* x      = (const float*)d_in[0];
    const float* ew1    = (const float*)d_in[1];
    const float* eg1    = (const float*)d_in[2];
    const float* eb1    = (const float*)d_in[3];
    const float* ew2    = (const float*)d_in[4];
    const float* eg2    = (const float*)d_in[5];
    const float* eb2    = (const float*)d_in[6];
    const float* ew3    = (const float*)d_in[7];
    const float* eg3    = (const float*)d_in[8];
    const float* eb3    = (const float*)d_in[9];
    const float* emb    = (const float*)d_in[10];
    const float* dw1    = (const float*)d_in[11];
    const float* dg1    = (const float*)d_in[12];
    const float* db1    = (const float*)d_in[13];
    const float* dw2    = (const float*)d_in[14];
    const float* dg2    = (const float*)d_in[15];
    const float* db2    = (const float*)d_in[16];
    const float* dw3    = (const float*)d_in[17];
    const float* dbias3 = (const float*)d_in[18];

    float* out_lat = (float*)d_out;                    // [64,4,32,32]
    float* out_q   = out_lat + 262144;                 // [64,4,32,32]
    float* out_dec = out_q + 262144;                   // [64,3,256,256]
    float* out_cb  = (float*)d_out + 13107200;
    float* out_cm  = out_cb + 1;

    // workspace layout (floats): 52.4 MB total
    float* bufA  = (float*)d_ws;          // max(h1 8258048, g2 8520768)
    float* bufB  = bufA + 8520768;        // max(h2 4194304, g1 4326400)
    float* bufC  = bufB + 4326400;        // conv3 raw out, 262144
    float* psum  = bufC + 262144;         // <=16*64
    float* psq   = psum + 1024;
    float* ssb   = psq + 1024;            // per-channel scale/shift, <=32
    float* lossp = ssb + 32;              // 256 partials

    const int T = 256;

    // ---- encoder stage 1: 3->8, 5x5 s2 p1, 256->127
    conv_fwd<3, 8, 5, 5, 2, 1, 256, 256, 127, 127>
        <<<dim3(64, 8, 64), T, 0, stream>>>(x, ew1, bufA);
    red_partial_k<8, 16129><<<dim3(8, 64), T, 0, stream>>>(bufA, psum, psq);
    red_final_k<8><<<8, 64, 0, stream>>>(psum, psq, eg1, eb1, ssb, 1.f / (64.f * 16129.f), 64);
    bnrelu_k<8, 16129><<<(8258048 + T - 1) / T, T, 0, stream>>>(bufA, bufA, ssb, 8258048);

    // ---- encoder stage 2: 8->16, 3x3 s2 p1, 127->64
    conv_fwd<8, 16, 3, 3, 2, 1, 127, 127, 64, 64>
        <<<dim3(16, 16, 64), T, 0, stream>>>(bufA, ew2, bufB);
    red_partial_k<16, 4096><<<dim3(16, 64), T, 0, stream>>>(bufB, psum, psq);
    red_final_k<16><<<16, 64, 0, stream>>>(psum, psq, eg2, eb2, ssb, 1.f / (64.f * 4096.f), 64);
    bnrelu_k<16, 4096><<<4194304 / T, T, 0, stream>>>(bufB, bufB, ssb, 4194304);

    // ---- encoder stage 3: 16->4, 3x3 s2 p1, 64->32 (latents)
    conv_fwd<16, 4, 3, 3, 2, 1, 64, 64, 32, 32>
        <<<dim3(4, 4, 64), T, 0, stream>>>(bufB, ew3, bufC);
    red_partial_k<4, 1024><<<dim3(4, 64), T, 0, stream>>>(bufC, psum, psq);
    red_final_k<4><<<4, 64, 0, stream>>>(psum, psq, eg3, eb3, ssb, 1.f / (64.f * 1024.f), 64);
    bnrelu_k<4, 1024><<<262144 / T, T, 0, stream>>>(bufC, out_lat, ssb, 262144);

    // ---- vector quantization (+ losses)
    vq_k<<<256, 256, 0, stream>>>(out_lat, emb, out_q, lossp);
    loss_final_k<<<1, 256, 0, stream>>>(lossp, out_cb, out_cm);

    // ---- decoder stage 1: convT 4->16, 3x3 s2 p0, 32->65
    convT_fwd<4, 16, 3, 3, 2, 0, 32, 32, 65, 65, false>
        <<<dim3(17, 16, 64), T, 0, stream>>>(out_q, dw1, nullptr, bufB);
    red_partial_k<16, 4225><<<dim3(16, 64), T, 0, stream>>>(bufB, psum, psq);
    red_final_k<16><<<16, 64, 0, stream>>>(psum, psq, dg1, db1, ssb, 1.f / (64.f * 4225.f), 64);
    bnrelu_k<16, 4225><<<(4326400 + T - 1) / T, T, 0, stream>>>(bufB, bufB, ssb, 4326400);

    // ---- decoder stage 2: convT 16->8, 3x3 s2 p1, 65->129
    convT_fwd<16, 8, 3, 3, 2, 1, 65, 65, 129, 129, false>
        <<<dim3(66, 8, 64), T, 0, stream>>>(bufB, dw2, nullptr, bufA);
    red_partial_k<8, 16641><<<dim3(8, 64), T, 0, stream>>>(bufA, psum, psq);
    red_final_k<8><<<8, 64, 0, stream>>>(psum, psq, dg2, db2, ssb, 1.f / (64.f * 16641.f), 64);
    bnrelu_k<8, 16641><<<(8520768 + T - 1) / T, T, 0, stream>>>(bufA, bufA, ssb, 8520768);

    // ---- decoder stage 3: convT 8->3, 2x2 s2 p1, 129->256, +bias, sigmoid
    convT_fwd<8, 3, 2, 2, 2, 1, 129, 129, 256, 256, true>
        <<<dim3(256, 3, 64), T, 0, stream>>>(bufA, dw3, dbias3, out_dec);
}

// Round 2
// 504.845 us; speedup vs baseline: 1.8663x; 1.8663x over previous
//
#include <hip/hip_runtime.h>
#include <hip/hip_bf16.h>
#include <math.h>

// ---------------------------------------------------------------------------
// VQ-VAE forward. B=64, CIN=3, H=W=256, K=512, D=4, f32.
// Round 2: all-COUT-per-thread convs, BN+ReLU fused into consumer loads,
// stats partials fused into conv epilogue.
// ---------------------------------------------------------------------------

#define EPSV 1e-5f

// ---------------- conv (NCHW in, OIHW w), thread = (n, pixel), all COUT -----
template<int CIN, int COUT, int KH, int KW, int S, int P,
         int IH, int IW, int OH, int OW, bool FUSE>
__global__ __launch_bounds__(256)
void conv_all(const float* __restrict__ in, const float* __restrict__ w,
              const float* __restrict__ ssin, float* __restrict__ out,
              float* __restrict__ psum, float* __restrict__ psq) {
    __shared__ float wl[COUT * CIN * KH * KW];
    __shared__ float ssl[2 * CIN];
    __shared__ float redbuf[4 * 2 * COUT];
    const int n = blockIdx.z;
    for (int i = threadIdx.x; i < COUT * CIN * KH * KW; i += 256) wl[i] = w[i];
    if constexpr (FUSE) {
        for (int i = threadIdx.x; i < 2 * CIN; i += 256) ssl[i] = ssin[i];
    }
    __syncthreads();

    const int p = blockIdx.x * 256 + threadIdx.x;
    const int oy = p / OW, ox = p % OW;
    float acc[COUT];
    #pragma unroll
    for (int co = 0; co < COUT; ++co) acc[co] = 0.f;

    if (p < OH * OW) {
        const int iy0 = oy * S - P, ix0 = ox * S - P;
        const float* inb = in + (size_t)n * CIN * IH * IW;
        #pragma unroll
        for (int ci = 0; ci < CIN; ++ci) {
            #pragma unroll
            for (int kh = 0; kh < KH; ++kh) {
                const int iy = iy0 + kh;
                if ((unsigned)iy < (unsigned)IH) {
                    #pragma unroll
                    for (int kw = 0; kw < KW; ++kw) {
                        const int ix = ix0 + kw;
                        if ((unsigned)ix < (unsigned)IW) {
                            float v = inb[(ci * IH + iy) * IW + ix];
                            if constexpr (FUSE)
                                v = fmaxf(v * ssl[2 * ci] + ssl[2 * ci + 1], 0.f);
                            #pragma unroll
                            for (int co = 0; co < COUT; ++co)
                                acc[co] += v * wl[((co * CIN + ci) * KH + kh) * KW + kw];
                        }
                    }
                }
            }
        }
        #pragma unroll
        for (int co = 0; co < COUT; ++co)
            out[(((size_t)n * COUT + co) * OH + oy) * OW + ox] = acc[co];
    }

    // ---- fused per-block stats partials (sum, sumsq per channel) ----
    const int lane = threadIdx.x & 63, wid = threadIdx.x >> 6;
    #pragma unroll
    for (int co = 0; co < COUT; ++co) {
        float s = acc[co], q = acc[co] * acc[co];
        #pragma unroll
        for (int o = 32; o > 0; o >>= 1) {
            s += __shfl_down(s, o, 64);
            q += __shfl_down(q, o, 64);
        }
        if (lane == 0) {
            redbuf[wid * 2 * COUT + 2 * co]     = s;
            redbuf[wid * 2 * COUT + 2 * co + 1] = q;
        }
    }
    __syncthreads();
    if (threadIdx.x < 2 * COUT) {
        const float v = redbuf[threadIdx.x] + redbuf[2 * COUT + threadIdx.x]
                      + redbuf[4 * COUT + threadIdx.x] + redbuf[6 * COUT + threadIdx.x];
        const int co = threadIdx.x >> 1;
        const int bid = blockIdx.z * gridDim.x + blockIdx.x;
        const int NB  = gridDim.x * gridDim.z;
        if (threadIdx.x & 1) psq[co * NB + bid] = v;
        else                 psum[co * NB + bid] = v;
    }
}

// ---------------- transposed conv (w: CIN,COUT,KH,KW), all COUT -------------
template<int CIN, int COUT, int KH, int KW, int P,
         int IH, int IW, int OH, int OW, bool FUSE>
__global__ __launch_bounds__(256)
void convT_all(const float* __restrict__ in, const float* __restrict__ w,
               const float* __restrict__ ssin, float* __restrict__ out,
               float* __restrict__ psum, float* __restrict__ psq) {
    __shared__ float wl[CIN * COUT * KH * KW];
    __shared__ float ssl[2 * CIN];
    __shared__ float redbuf[4 * 2 * COUT];
    const int n = blockIdx.z;
    for (int i = threadIdx.x; i < CIN * COUT * KH * KW; i += 256) wl[i] = w[i];
    if constexpr (FUSE) {
        for (int i = threadIdx.x; i < 2 * CIN; i += 256) ssl[i] = ssin[i];
    }
    __syncthreads();

    const int p = blockIdx.x * 256 + threadIdx.x;
    const int oy = p / OW, ox = p % OW;
    float acc[COUT];
    #pragma unroll
    for (int co = 0; co < COUT; ++co) acc[co] = 0.f;

    if (p < OH * OW) {
        const float* inb = in + (size_t)n * CIN * IH * IW;
        #pragma unroll
        for (int kh = 0; kh < KH; ++kh) {
            const int t = oy + P - kh;
            const int iy = t >> 1;                       // S==2
            if (t >= 0 && (t & 1) == 0 && iy < IH) {
                #pragma unroll
                for (int kw = 0; kw < KW; ++kw) {
                    const int u = ox + P - kw;
                    const int ix = u >> 1;
                    if (u >= 0 && (u & 1) == 0 && ix < IW) {
                        #pragma unroll
                        for (int ci = 0; ci < CIN; ++ci) {
                            float v = inb[(ci * IH + iy) * IW + ix];
                            if constexpr (FUSE)
                                v = fmaxf(v * ssl[2 * ci] + ssl[2 * ci + 1], 0.f);
                            #pragma unroll
                            for (int co = 0; co < COUT; ++co)
                                acc[co] += v * wl[((ci * COUT + co) * KH + kh) * KW + kw];
                        }
                    }
                }
            }
        }
        #pragma unroll
        for (int co = 0; co < COUT; ++co)
            out[(((size_t)n * COUT + co) * OH + oy) * OW + ox] = acc[co];
    }

    const int lane = threadIdx.x & 63, wid = threadIdx.x >> 6;
    #pragma unroll
    for (int co = 0; co < COUT; ++co) {
        float s = acc[co], q = acc[co] * acc[co];
        #pragma unroll
        for (int o = 32; o > 0; o >>= 1) {
            s += __shfl_down(s, o, 64);
            q += __shfl_down(q, o, 64);
        }
        if (lane == 0) {
            redbuf[wid * 2 * COUT + 2 * co]     = s;
            redbuf[wid * 2 * COUT + 2 * co + 1] = q;
        }
    }
    __syncthreads();
    if (threadIdx.x < 2 * COUT) {
        const float v = redbuf[threadIdx.x] + redbuf[2 * COUT + threadIdx.x]
                      + redbuf[4 * COUT + threadIdx.x] + redbuf[6 * COUT + threadIdx.x];
        const int co = threadIdx.x >> 1;
        const int bid = blockIdx.z * gridDim.x + blockIdx.x;
        const int NB  = gridDim.x * gridDim.z;
        if (threadIdx.x & 1) psq[co * NB + bid] = v;
        else                 psum[co * NB + bid] = v;
    }
}

// ---------------- stats finalize: per-channel scale/shift -------------------
template<int C>
__global__ __launch_bounds__(64)
void red_final_k(const float* __restrict__ psum, const float* __restrict__ psq,
                 const float* __restrict__ g, const float* __restrict__ b,
                 float* __restrict__ ss, float inv_count, int NB) {
    const int c = blockIdx.x;
    float s = 0.f, q = 0.f;
    for (int i = threadIdx.x; i < NB; i += 64) { s += psum[c * NB + i]; q += psq[c * NB + i]; }
    #pragma unroll
    for (int o = 32; o > 0; o >>= 1) {
        s += __shfl_down(s, o, 64);
        q += __shfl_down(q, o, 64);
    }
    if (threadIdx.x == 0) {
        const float mean = s * inv_count;
        const float var  = q * inv_count - mean * mean;
        const float rstd = 1.f / sqrtf(var + EPSV);
        const float sc   = g[c] * rstd;
        ss[2 * c]     = sc;
        ss[2 * c + 1] = b[c] - mean * sc;
    }
}

// ---------------- VQ with fused BN+ReLU of latents --------------------------
__global__ __launch_bounds__(256)
void vq_k(const float* __restrict__ raw, const float* __restrict__ ss,
          const float* __restrict__ emb, float* __restrict__ out_lat,
          float* __restrict__ out_q, float* __restrict__ lossp) {
    __shared__ float e[512 * 4];
    __shared__ float ee[512];
    __shared__ float ssl[8];
    __shared__ float redbuf[4];
    for (int i = threadIdx.x; i < 512 * 4; i += 256) e[i] = emb[i];
    if (threadIdx.x < 8) ssl[threadIdx.x] = ss[threadIdx.x];
    __syncthreads();
    for (int k = threadIdx.x; k < 512; k += 256) {
        float s = 0.f;
        #pragma unroll
        for (int d = 0; d < 4; ++d) { const float v = e[k * 4 + d]; s += v * v; }
        ee[k] = s;
    }
    __syncthreads();

    const int t = blockIdx.x * 256 + threadIdx.x;     // token id, 65536 exact
    const int b = t >> 10, p = t & 1023;
    const float* rb = raw + ((size_t)b * 4) * 1024 + p;
    const float z0 = fmaxf(rb[0]    * ssl[0] + ssl[1], 0.f);
    const float z1 = fmaxf(rb[1024] * ssl[2] + ssl[3], 0.f);
    const float z2 = fmaxf(rb[2048] * ssl[4] + ssl[5], 0.f);
    const float z3 = fmaxf(rb[3072] * ssl[6] + ssl[7], 0.f);
    float* lb = out_lat + ((size_t)b * 4) * 1024 + p;
    lb[0] = z0; lb[1024] = z1; lb[2048] = z2; lb[3072] = z3;

    const float zz = z0 * z0 + z1 * z1 + z2 * z2 + z3 * z3;
    int best = 0;
    float bd = INFINITY;
    #pragma unroll 8
    for (int k = 0; k < 512; ++k) {
        const float dot = z0 * e[k * 4] + z1 * e[k * 4 + 1] + z2 * e[k * 4 + 2] + z3 * e[k * 4 + 3];
        const float d = zz - 2.f * dot + ee[k];       // expanded form, as reference
        if (d < bd) { bd = d; best = k; }             // strict < = first-occurrence argmin
    }
    const float q0 = e[best * 4], q1 = e[best * 4 + 1], q2 = e[best * 4 + 2], q3 = e[best * 4 + 3];
    float* qb = out_q + ((size_t)b * 4) * 1024 + p;
    qb[0] = q0; qb[1024] = q1; qb[2048] = q2; qb[3072] = q3;

    float ssd = (q0 - z0) * (q0 - z0) + (q1 - z1) * (q1 - z1)
              + (q2 - z2) * (q2 - z2) + (q3 - z3) * (q3 - z3);
    #pragma unroll
    for (int o = 32; o > 0; o >>= 1) ssd += __shfl_down(ssd, o, 64);
    const int lane = threadIdx.x & 63, wid = threadIdx.x >> 6;
    if (lane == 0) redbuf[wid] = ssd;
    __syncthreads();
    if (threadIdx.x == 0)
        lossp[blockIdx.x] = redbuf[0] + redbuf[1] + redbuf[2] + redbuf[3];
}

__global__ __launch_bounds__(256)
void loss_final_k(const float* __restrict__ partial, float* __restrict__ out_cb,
                  float* __restrict__ out_cm) {
    __shared__ float redbuf[4];
    float s = partial[threadIdx.x];                    // 256 partials
    #pragma unroll
    for (int o = 32; o > 0; o >>= 1) s += __shfl_down(s, o, 64);
    const int lane = threadIdx.x & 63, wid = threadIdx.x >> 6;
    if (lane == 0) redbuf[wid] = s;
    __syncthreads();
    if (threadIdx.x == 0) {
        const float L = (redbuf[0] + redbuf[1] + redbuf[2] + redbuf[3]) * (1.f / 262144.f);
        *out_cb = L;
        *out_cm = L;
    }
}

// ---------------- decoder stage 3 specialized: k2 s2 p1 -> exactly 1 tap ----
__global__ __launch_bounds__(256)
void convt3_k(const float* __restrict__ in, const float* __restrict__ w,
              const float* __restrict__ ss, const float* __restrict__ bias,
              float* __restrict__ out) {
    __shared__ float wl[8 * 3 * 4];
    __shared__ float ssl[16];
    __shared__ float bl[3];
    if (threadIdx.x < 96) wl[threadIdx.x] = w[threadIdx.x];
    if (threadIdx.x < 16) ssl[threadIdx.x] = ss[threadIdx.x];
    if (threadIdx.x < 3)  bl[threadIdx.x] = bias[threadIdx.x];
    __syncthreads();

    const int n = blockIdx.z;
    const int p = blockIdx.x * 256 + threadIdx.x;      // 65536 exact
    const int oy = p >> 8, ox = p & 255;
    const int kh = 1 - (oy & 1), kw = 1 - (ox & 1);    // unique valid tap
    const int iy = (oy + 1 - kh) >> 1, ix = (ox + 1 - kw) >> 1;
    const float* inb = in + (size_t)n * 8 * 129 * 129;

    float a0 = bl[0], a1 = bl[1], a2 = bl[2];
    const int wo = kh * 2 + kw;
    #pragma unroll
    for (int ci = 0; ci < 8; ++ci) {
        float v = inb[(ci * 129 + iy) * 129 + ix];
        v = fmaxf(v * ssl[2 * ci] + ssl[2 * ci + 1], 0.f);
        a0 += v * wl[(ci * 3 + 0) * 4 + wo];
        a1 += v * wl[(ci * 3 + 1) * 4 + wo];
        a2 += v * wl[(ci * 3 + 2) * 4 + wo];
    }
    a0 = 1.f / (1.f + expf(-a0));
    a1 = 1.f / (1.f + expf(-a1));
    a2 = 1.f / (1.f + expf(-a2));
    float* ob = out + ((size_t)n * 3 * 65536) + (size_t)oy * 256 + ox;
    ob[0] = a0; ob[65536] = a1; ob[131072] = a2;
}

// ---------------------------------------------------------------------------
extern "C" void kernel_launch(void* const* d_in, const int* in_sizes, int n_in,
                              void* d_out, int out_size, void* d_ws, size_t ws_size,
                              hipStream_t stream) {
    const float* x      = (const float*)d_in[0];
    const float* ew1    = (const float*)d_in[1];
    const float* eg1    = (const float*)d_in[2];
    const float* eb1    = (const float*)d_in[3];
    const float* ew2    = (const float*)d_in[4];
    const float* eg2    = (const float*)d_in[5];
    const float* eb2    = (const float*)d_in[6];
    const float* ew3    = (const float*)d_in[7];
    const float* eg3    = (const float*)d_in[8];
    const float* eb3    = (const float*)d_in[9];
    const float* emb    = (const float*)d_in[10];
    const float* dw1    = (const float*)d_in[11];
    const float* dg1    = (const float*)d_in[12];
    const float* db1    = (const float*)d_in[13];
    const float* dw2    = (const float*)d_in[14];
    const float* dg2    = (const float*)d_in[15];
    const float* db2    = (const float*)d_in[16];
    const float* dw3    = (const float*)d_in[17];
    const float* dbias3 = (const float*)d_in[18];

    float* out_lat = (float*)d_out;
    float* out_q   = out_lat + 262144;
    float* out_dec = out_q + 262144;
    float* out_cb  = (float*)d_out + 13107200;
    float* out_cm  = out_cb + 1;

    float* bufA  = (float*)d_ws;          // max(h1 8258048, g2 8520768)
    float* bufB  = bufA + 8520768;        // max(h2 4194304, g1 4326400)
    float* bufC  = bufB + 4326400;        // conv3 raw, 262144
    float* psum  = bufC + 262144;         // <= 8*4224 = 33792
    float* psq   = psum + 33792;
    float* ssb   = psq + 33792;           // scale/shift pairs, <=32
    float* lossp = ssb + 32;              // 256

    const int T = 256;

    // encoder 1: 3->8, 5x5 s2 p1, 256->127 (no input fuse)
    conv_all<3, 8, 5, 5, 2, 1, 256, 256, 127, 127, false>
        <<<dim3(64, 1, 64), T, 0, stream>>>(x, ew1, nullptr, bufA, psum, psq);
    red_final_k<8><<<8, 64, 0, stream>>>(psum, psq, eg1, eb1, ssb,
                                         1.f / (64.f * 16129.f), 64 * 64);

    // encoder 2: 8->16, 3x3 s2 p1, 127->64 (BN1+ReLU fused on load)
    conv_all<8, 16, 3, 3, 2, 1, 127, 127, 64, 64, true>
        <<<dim3(16, 1, 64), T, 0, stream>>>(bufA, ew2, ssb, bufB, psum, psq);
    red_final_k<16><<<16, 64, 0, stream>>>(psum, psq, eg2, eb2, ssb,
                                           1.f / (64.f * 4096.f), 16 * 64);

    // encoder 3: 16->4, 3x3 s2 p1, 64->32 (BN2+ReLU fused on load)
    conv_all<16, 4, 3, 3, 2, 1, 64, 64, 32, 32, true>
        <<<dim3(4, 1, 64), T, 0, stream>>>(bufB, ew3, ssb, bufC, psum, psq);
    red_final_k<4><<<4, 64, 0, stream>>>(psum, psq, eg3, eb3, ssb,
                                         1.f / (64.f * 1024.f), 4 * 64);

    // VQ (+ BN3+ReLU fused, latents written here) + losses
    vq_k<<<256, T, 0, stream>>>(bufC, ssb, emb, out_lat, out_q, lossp);
    loss_final_k<<<1, T, 0, stream>>>(lossp, out_cb, out_cm);

    // decoder 1: convT 4->16, 3x3 s2 p0, 32->65
    convT_all<4, 16, 3, 3, 0, 32, 32, 65, 65, false>
        <<<dim3(17, 1, 64), T, 0, stream>>>(out_q, dw1, nullptr, bufB, psum, psq);
    red_final_k<16><<<16, 64, 0, stream>>>(psum, psq, dg1, db1, ssb,
                                           1.f / (64.f * 4225.f), 17 * 64);

    // decoder 2: convT 16->8, 3x3 s2 p1, 65->129 (BN+ReLU fused on load)
    convT_all<16, 8, 3, 3, 1, 65, 65, 129, 129, true>
        <<<dim3(66, 1, 64), T, 0, stream>>>(bufB, dw2, ssb, bufA, psum, psq);
    red_final_k<8><<<8, 64, 0, stream>>>(psum, psq, dg2, db2, ssb,
                                         1.f / (64.f * 16641.f), 66 * 64);

    // decoder 3: convT 8->3, 2x2 s2 p1, 129->256, BN+ReLU fused, +bias+sigmoid
    convt3_k<<<dim3(256, 1, 64), T, 0, stream>>>(bufA, dw3, ssb, dbias3, out_dec);
}